// Round 1
// baseline (84.818 us; speedup 1.0000x reference)
//
#include <hip/hip_runtime.h>
#include <math.h>

// VQC: batch=16384, n_qubits=8 (dim=256), n_layers=2.
// One 64-lane wave per batch element; each lane holds 4 complex amplitudes
// b = (lane<<2)|j. Index-bit p gates: p<2 within lane, p>=2 via __shfl_xor.
// Gate matrices (param-only) computed once per block into LDS.

__global__ __launch_bounds__(256) void vqc_kernel(const float* __restrict__ inputs,
                                                  const float* __restrict__ params,
                                                  float* __restrict__ out,
                                                  int batch) {
    __shared__ float Us[16 * 8];  // per gate g: U00re,U00im,U01re,U01im,U10re,U10im,U11re,U11im
    const int tid = threadIdx.x;

    if (tid < 16) {
        const int l = tid >> 3, q = tid & 7;
        const float th = 0.5f * params[l * 16 + q * 2 + 0];  // RY half-angle
        const float ph = 0.5f * params[l * 16 + q * 2 + 1];  // RZ half-angle
        const float cy = __cosf(th), sy = __sinf(th);
        const float cp = __cosf(ph), sp = __sinf(ph);
        float* u = &Us[tid * 8];
        // U = RZ(phi) @ RY(theta); em = exp(-i ph), ep = exp(+i ph)
        u[0] =  cp * cy;  u[1] = -sp * cy;   // U00 =  em*cy
        u[2] = -cp * sy;  u[3] =  sp * sy;   // U01 = -em*sy
        u[4] =  cp * sy;  u[5] =  sp * sy;   // U10 =  ep*sy
        u[6] =  cp * cy;  u[7] =  sp * cy;   // U11 =  ep*cy
    }
    __syncthreads();

    const int lane = tid & 63;
    const int w = blockIdx.x * 4 + (tid >> 6);  // batch element for this wave
    if (w >= batch) return;

    // ---- initial product state from RX(inputs) ----
    const float x = inputs[w * 8 + (lane & 7)];
    const float ch = __cosf(0.5f * x), sh = __sinf(0.5f * x);
    float cq[8], sq[8];
#pragma unroll
    for (int q = 0; q < 8; ++q) {
        cq[q] = __shfl(ch, q, 64);
        sq[q] = __shfl(sh, q, 64);
    }

    float sre[4], sim[4];
#pragma unroll
    for (int j = 0; j < 4; ++j) {
        const int b = (lane << 2) | j;
        float r = 1.0f;
#pragma unroll
        for (int q = 0; q < 8; ++q)           // qubit q = index bit (7-q)
            r *= ((b >> (7 - q)) & 1) ? sq[q] : cq[q];
        const int k = __popc(b) & 3;          // phase (-i)^popcount
        sre[j] = (k == 0) ? r : ((k == 2) ? -r : 0.0f);
        sim[j] = (k == 1) ? -r : ((k == 3) ? r : 0.0f);
    }

    // ---- variational layers ----
#pragma unroll
    for (int l = 0; l < 2; ++l) {
        // qubits 0..5 -> index bits 7..2 -> cross-lane bit xb = 5-q
#pragma unroll
        for (int q = 0; q < 6; ++q) {
            const float* u = &Us[(l * 8 + q) * 8];
            const int xb = 5 - q;
            const int m = 1 << xb;
            const int myb = (lane >> xb) & 1;
            const float Are = myb ? u[6] : u[0], Aim = myb ? u[7] : u[1];  // coeff on my amp
            const float Bre = myb ? u[4] : u[2], Bim = myb ? u[5] : u[3];  // coeff on partner
#pragma unroll
            for (int j = 0; j < 4; ++j) {
                const float ore = __shfl_xor(sre[j], m, 64);
                const float oim = __shfl_xor(sim[j], m, 64);
                const float nre = Are * sre[j] - Aim * sim[j] + Bre * ore - Bim * oim;
                const float nim = Are * sim[j] + Aim * sre[j] + Bre * oim + Bim * ore;
                sre[j] = nre; sim[j] = nim;
            }
        }
        // qubits 6,7 -> index bits 1,0 -> within-lane pairs over j
#pragma unroll
        for (int q = 6; q < 8; ++q) {
            const float* u = &Us[(l * 8 + q) * 8];
            const int m = 1 << (7 - q);
#pragma unroll
            for (int j0 = 0; j0 < 4; ++j0) {
                if (j0 & m) continue;
                const int j1 = j0 | m;
                const float a0r = sre[j0], a0i = sim[j0];
                const float a1r = sre[j1], a1i = sim[j1];
                sre[j0] = u[0] * a0r - u[1] * a0i + u[2] * a1r - u[3] * a1i;
                sim[j0] = u[0] * a0i + u[1] * a0r + u[2] * a1i + u[3] * a1r;
                sre[j1] = u[4] * a0r - u[5] * a0i + u[6] * a1r - u[7] * a1i;
                sim[j1] = u[4] * a0i + u[5] * a0r + u[6] * a1i + u[7] * a1r;
            }
        }
        // CZ ring: sign = (-1)^popcount(b & rotl8(b,1))
#pragma unroll
        for (int j = 0; j < 4; ++j) {
            const int b = (lane << 2) | j;
            const int rot = ((b << 1) | (b >> 7)) & 255;
            if (__popc(b & rot) & 1) { sre[j] = -sre[j]; sim[j] = -sim[j]; }
        }
    }

    // ---- readouts: <Z0 Z1> (bits 7,6) and <Z2..Z7> (bits 5..0) ----
    float sa = 0.0f, sb = 0.0f;
#pragma unroll
    for (int j = 0; j < 4; ++j) {
        const int b = (lane << 2) | j;
        const float p = sre[j] * sre[j] + sim[j] * sim[j];
        sa += (((b >> 7) ^ (b >> 6)) & 1) ? -p : p;
        sb += (__popc(b & 0x3F) & 1) ? -p : p;
    }
#pragma unroll
    for (int off = 32; off >= 1; off >>= 1) {
        sa += __shfl_xor(sa, off, 64);
        sb += __shfl_xor(sb, off, 64);
    }
    if (lane == 0) {
        out[w * 2 + 0] = sa;
        out[w * 2 + 1] = sb;
    }
}

extern "C" void kernel_launch(void* const* d_in, const int* in_sizes, int n_in,
                              void* d_out, int out_size, void* d_ws, size_t ws_size,
                              hipStream_t stream) {
    const float* inputs = (const float*)d_in[0];
    const float* params = (const float*)d_in[1];
    float* out = (float*)d_out;
    const int batch = in_sizes[0] / 8;           // (B, 8) f32
    const int blocks = (batch + 3) / 4;          // 4 waves (batch elems) per 256-thread block
    vqc_kernel<<<blocks, 256, 0, stream>>>(inputs, params, out, batch);
}

// Round 2
// 81.015 us; speedup vs baseline: 1.0469x; 1.0469x over previous
//
#include <hip/hip_runtime.h>
#include <math.h>

// VQC: batch=16384, n_qubits=8 (dim=256), n_layers=2.
// 16 lanes per batch element (4 elements per 64-lane wave); each lane holds
// 16 complex amplitudes b = (r<<4)|j where r = lane&15 (index bits 7..4,
// qubits 0..3) and j = local index (bits 3..0, qubits 4..7).
// Cross-lane gates (qubits 0..3) via __shfl_xor with mask<=8 (stays inside
// the 16-lane group); qubits 4..7 are within-lane pair updates.
// Gate matrices (param-only) computed once per block into LDS (broadcast
// reads, conflict-free).

__global__ __launch_bounds__(256) void vqc_kernel(const float* __restrict__ inputs,
                                                  const float* __restrict__ params,
                                                  float* __restrict__ out,
                                                  int batch) {
    __shared__ float Us[16 * 8];  // per gate: U00re,U00im,U01re,U01im,U10re,U10im,U11re,U11im
    const int tid = threadIdx.x;

    if (tid < 16) {
        const int l = tid >> 3, q = tid & 7;
        const float th = 0.5f * params[l * 16 + q * 2 + 0];  // RY half-angle
        const float ph = 0.5f * params[l * 16 + q * 2 + 1];  // RZ half-angle
        const float cy = __cosf(th), sy = __sinf(th);
        const float cp = __cosf(ph), sp = __sinf(ph);
        float* u = &Us[tid * 8];
        // U = RZ(phi) @ RY(theta); em = exp(-i ph), ep = exp(+i ph)
        u[0] =  cp * cy;  u[1] = -sp * cy;   // U00 =  em*cy
        u[2] = -cp * sy;  u[3] =  sp * sy;   // U01 = -em*sy
        u[4] =  cp * sy;  u[5] =  sp * sy;   // U10 =  ep*sy
        u[6] =  cp * cy;  u[7] =  sp * cy;   // U11 =  ep*cy
    }
    __syncthreads();

    const int lane = tid & 63;
    const int g = lane >> 4;      // element slot within wave (0..3)
    const int r = lane & 15;      // sub-lane = index bits 7..4 (qubits 0..3)
    const int w = blockIdx.x * 16 + (tid >> 6) * 4 + g;
    if (w >= batch) return;       // uniform per 16-lane group; shuffles stay valid

    // ---- initial product state from RX(inputs) ----
    const float x = inputs[w * 8 + (r & 7)];
    const float ch = __cosf(0.5f * x), sh = __sinf(0.5f * x);
    float cq[8], sq[8];
#pragma unroll
    for (int q = 0; q < 8; ++q) {
        cq[q] = __shfl(ch, (g << 4) | q, 64);
        sq[q] = __shfl(sh, (g << 4) | q, 64);
    }

    // lane factor over qubits 0..3 (bits of r, MSB-first)
    float lf = 1.0f;
#pragma unroll
    for (int q = 0; q < 4; ++q)
        lf *= ((r >> (3 - q)) & 1) ? sq[q] : cq[q];
    const int pr = __popc(r);

    float sre[16], sim[16];
#pragma unroll
    for (int j = 0; j < 16; ++j) {
        float v = lf;
        v *= (j & 8) ? sq[4] : cq[4];  // bit3 of j = qubit 4
        v *= (j & 4) ? sq[5] : cq[5];
        v *= (j & 2) ? sq[6] : cq[6];
        v *= (j & 1) ? sq[7] : cq[7];
        const int k = (pr + __popc(j)) & 3;  // phase (-i)^popcount(b)
        sre[j] = (k == 0) ? v : ((k == 2) ? -v : 0.0f);
        sim[j] = (k == 1) ? -v : ((k == 3) ? v : 0.0f);
    }

    // ---- variational layers ----
#pragma unroll
    for (int l = 0; l < 2; ++l) {
        // qubits 0..3: cross-lane, lane-bit (3-q), mask <= 8 (within group)
#pragma unroll
        for (int q = 0; q < 4; ++q) {
            const float* u = &Us[(l * 8 + q) * 8];
            const int m = 1 << (3 - q);
            const int myb = (r >> (3 - q)) & 1;
            const float Are = myb ? u[6] : u[0], Aim = myb ? u[7] : u[1];
            const float Bre = myb ? u[4] : u[2], Bim = myb ? u[5] : u[3];
#pragma unroll
            for (int j = 0; j < 16; ++j) {
                const float ore = __shfl_xor(sre[j], m, 64);
                const float oim = __shfl_xor(sim[j], m, 64);
                const float nre = Are * sre[j] - Aim * sim[j] + Bre * ore - Bim * oim;
                const float nim = Are * sim[j] + Aim * sre[j] + Bre * oim + Bim * ore;
                sre[j] = nre; sim[j] = nim;
            }
        }
        // qubits 4..7: within-lane pairs over j (j-bit 1<<(7-q))
#pragma unroll
        for (int q = 4; q < 8; ++q) {
            const float* u = &Us[(l * 8 + q) * 8];
            const int m = 1 << (7 - q);
#pragma unroll
            for (int j0 = 0; j0 < 16; ++j0) {
                if (j0 & m) continue;
                const int j1 = j0 | m;
                const float a0r = sre[j0], a0i = sim[j0];
                const float a1r = sre[j1], a1i = sim[j1];
                sre[j0] = u[0] * a0r - u[1] * a0i + u[2] * a1r - u[3] * a1i;
                sim[j0] = u[0] * a0i + u[1] * a0r + u[2] * a1i + u[3] * a1r;
                sre[j1] = u[4] * a0r - u[5] * a0i + u[6] * a1r - u[7] * a1i;
                sim[j1] = u[4] * a0i + u[5] * a0r + u[6] * a1i + u[7] * a1r;
            }
        }
        // CZ ring: sign = (-1)^popcount(b & rotl8(b,1))
#pragma unroll
        for (int j = 0; j < 16; ++j) {
            const int b = (r << 4) | j;
            const int rot = ((b << 1) | (b >> 7)) & 255;
            if (__popc(b & rot) & 1) { sre[j] = -sre[j]; sim[j] = -sim[j]; }
        }
    }

    // ---- readouts: <Z0 Z1> (bits 7,6 -> r bits 3,2) and <Z2..Z7> (bits 5..0) ----
    float sa = 0.0f, sb = 0.0f;
    const int pr2 = __popc(r & 3);
#pragma unroll
    for (int j = 0; j < 16; ++j) {
        const float p = sre[j] * sre[j] + sim[j] * sim[j];
        sa += p;  // per-lane-uniform sign applied after the loop
        sb += ((pr2 + __popc(j)) & 1) ? -p : p;
    }
    if (((r >> 3) ^ (r >> 2)) & 1) sa = -sa;
    // reduce over the 16-lane group
#pragma unroll
    for (int off = 8; off >= 1; off >>= 1) {
        sa += __shfl_xor(sa, off, 64);
        sb += __shfl_xor(sb, off, 64);
    }
    if (r == 0) {
        out[w * 2 + 0] = sa;
        out[w * 2 + 1] = sb;
    }
}

extern "C" void kernel_launch(void* const* d_in, const int* in_sizes, int n_in,
                              void* d_out, int out_size, void* d_ws, size_t ws_size,
                              hipStream_t stream) {
    const float* inputs = (const float*)d_in[0];
    const float* params = (const float*)d_in[1];
    float* out = (float*)d_out;
    const int batch = in_sizes[0] / 8;            // (B, 8) f32
    const int blocks = (batch + 15) / 16;         // 16 elements per 256-thread block
    vqc_kernel<<<blocks, 256, 0, stream>>>(inputs, params, out, batch);
}